// Round 21
// baseline (95.552 us; speedup 1.0000x reference)
//
#include <hip/hip_runtime.h>
#include <hip/hip_bf16.h>
#include <stdint.h>
#include <math.h>

typedef __attribute__((ext_vector_type(8))) short short8;
typedef __attribute__((ext_vector_type(4))) short short4v;
typedef __attribute__((ext_vector_type(4))) float float4v;

#define MFMA16(a,b,c) __builtin_amdgcn_mfma_f32_16x16x32_bf16((a),(b),(c),0,0,0)
#define MFMA16K16(a,b,c) __builtin_amdgcn_mfma_f32_16x16x16bf16_1k((a),(b),(c),0,0,0)

__device__ __forceinline__ short bf16r(float f) {
  union { float f; uint32_t u; } v; v.f = f;
  uint32_t r = v.u + 0x7fffu + ((v.u >> 16) & 1u);
  return (short)(r >> 16);
}
__device__ __forceinline__ float bf2f(short s) {
  union { float f; uint32_t u; } v; v.u = ((uint32_t)(uint16_t)s) << 16;
  return v.f;
}
// packed f32x2 -> bf16x2 (lo = a, hi = b)
__device__ __forceinline__ uint32_t cvtpk(float a, float b) {
  uint32_t r;
  asm("v_cvt_pk_bf16_f32 %0, %1, %2" : "=v"(r) : "v"(a), "v"(b));
  return r;
}

__device__ __forceinline__ void gld_lds16(void* lds, const void* g) {
  __builtin_amdgcn_global_load_lds(
      (const __attribute__((address_space(1))) uint32_t*)g,
      (__attribute__((address_space(3))) uint32_t*)lds, 16, 0, 0);
}

// ---------------- Kernel 1: W transpose+convert (LDS transpose) -------------
__global__ __launch_bounds__(256) void prep_wt(
    const float* __restrict__ Wk, const float* __restrict__ Wq,
    const float* __restrict__ Wv, short* __restrict__ WT) {
  __shared__ float tile[64][65];
  const int w = blockIdx.y;
  const int k0 = blockIdx.x * 64;
  const float* W = (w == 0) ? Wk : (w == 1) ? Wq : Wv;
  const int tid = threadIdx.x;
#pragma unroll
  for (int i = 0; i < 16; ++i) {
    int e = i * 256 + tid;
    int kk = e >> 6, hh = e & 63;
    tile[kk][hh] = W[(size_t)(k0 + kk) * 64 + hh];
  }
  __syncthreads();
#pragma unroll
  for (int i = 0; i < 16; ++i) {
    int e = i * 256 + tid;
    int hh = e >> 6, kk = e & 63;
    WT[(size_t)w * 65536 + hh * 1024 + k0 + kk] = bf16r(tile[kk][hh]);
  }
}

// ---------------- Kernel 2: projection GEMM, BM=32, 2 blocks/CU -------------
// (validated R12) 512 blocks x 512 thr; wave w: m-tile w&1, n-triple w>>1.
// Qg pre-scaled by 0.125*log2(e) so attn uses native exp2.
__global__ __launch_bounds__(512, 4) void proj_kernel(
    const float* __restrict__ x, const short* __restrict__ WT,
    short* __restrict__ Kg, short* __restrict__ Qg, short* __restrict__ Vt) {
  __shared__ __align__(16) short xs[2][32][72];
  __shared__ __align__(16) short wts[2][192 * 64];
  const int tid = threadIdx.x;
  const int lane = tid & 63;
  const int w = tid >> 6;
  const int c = lane & 15;
  const int sl = lane >> 4;
  const int mh = w & 1;
  const int nh = w >> 1;
  const int m0 = blockIdx.x * 32;

  float4v acc[3];
#pragma unroll
  for (int ni = 0; ni < 3; ++ni) acc[ni] = (float4v){0.f, 0.f, 0.f, 0.f};

  const int srow = tid >> 4;
  const int scol = (tid & 15) * 4;
  const float* xrow = x + (size_t)(m0 + srow) * 1024 + scol;

#define PSTAGE_WT(buf, kk)                                                    \
  _Pragma("unroll") for (int rr = 0; rr < 3; ++rr) {                          \
    const int chunk = rr * 512 + tid;                                         \
    const int n = chunk >> 3;                                                 \
    const int cc = chunk & 7;                                                 \
    gld_lds16(wts[buf] + chunk * 8,                                           \
              WT + (size_t)n * 1024 + (kk) + ((cc ^ (n & 7)) * 8));           \
  }
#define PWRITE_X(buf)                                                         \
  {                                                                           \
    short4v hx;                                                               \
    hx.x = bf16r(xr.x); hx.y = bf16r(xr.y);                                   \
    hx.z = bf16r(xr.z); hx.w = bf16r(xr.w);                                   \
    *(short4v*)(&xs[buf][srow][scol]) = hx;                                   \
  }

  float4v xr = *(const float4v*)(xrow);
  float4v xn = *(const float4v*)(xrow + 64);

  PSTAGE_WT(0, 0)
  PWRITE_X(0)
  __syncthreads();

  int cur = 0;
  for (int it = 0; it < 16; ++it) {
    const int k0 = it * 64;
    if (it + 1 < 16) {
      PSTAGE_WT(cur ^ 1, k0 + 64)
      xr = xn;
      PWRITE_X(cur ^ 1)
      if (it + 2 < 16) xn = *(const float4v*)(xrow + k0 + 128);
    }
    short8 a0 = *(const short8*)(&xs[cur][mh * 16 + c][sl * 8]);
    short8 a1 = *(const short8*)(&xs[cur][mh * 16 + c][32 + sl * 8]);
#pragma unroll
    for (int ni = 0; ni < 3; ++ni) {
      const int rw = (nh * 3 + ni) * 16 + c;
      short8 b0 = *(const short8*)(wts[cur] + rw * 64 + ((sl ^ (rw & 7)) * 8));
      short8 b1 = *(const short8*)(wts[cur] + rw * 64 + (((sl + 4) ^ (rw & 7)) * 8));
      acc[ni] = MFMA16(a0, b0, acc[ni]);
      acc[ni] = MFMA16(a1, b1, acc[ni]);
    }
    __syncthreads();
    cur ^= 1;
  }
#undef PSTAGE_WT
#undef PWRITE_X

  const int b = m0 >> 12;
  const int s_base = m0 & 4095;
  const float QSCALE = 0.18033688011112042f;     // 0.125 * log2(e)
#pragma unroll
  for (int ni = 0; ni < 3; ++ni) {
    const int nt = nh * 3 + ni;
    const int wsel = nt >> 2;                    // 0:K 1:Q 2:V
    const int h = (nt & 3) * 16 + c;
    const int q_local = mh * 16 + sl * 4;
    if (wsel == 2) {
      short4v pv;
      pv.x = bf16r(acc[ni].x); pv.y = bf16r(acc[ni].y);
      pv.z = bf16r(acc[ni].z); pv.w = bf16r(acc[ni].w);
      *(short4v*)(Vt + (size_t)(b * 64 + h) * 4096 + s_base + q_local) = pv;
    } else if (wsel == 1) {
#pragma unroll
      for (int i = 0; i < 4; ++i)
        Qg[(size_t)(m0 + q_local + i) * 64 + h] = bf16r(acc[ni][i] * QSCALE);
    } else {
#pragma unroll
      for (int i = 0; i < 4; ++i)
        Kg[(size_t)(m0 + q_local + i) * 64 + h] = bf16r(acc[ni][i]);
    }
  }
}

// ---------------- Kernel 3: flash attention + fused combine -----------------
// R20 body byte-identical (8 waves x 16 q-rows, up-front staging, ONE
// barrier, shuffle-free K=16 PV, matrix-pipe lsum). NEW: combine fused via
// last-block atomic (R8-validated pattern). Safe here because (512,4) gives
// a 128-VGPR budget and the tail's live set (~110) fits — R10's regression
// was the (256,4)->64-reg squeeze, not the fusion itself. Deterministic:
// fixed i=0..nch-1 summation order regardless of arrival.
#define SLOT_BYTES 16896   // 128*64 bf16 o (16384) + 128 f32 l (512)
__global__ __launch_bounds__(512, 4) void attn_kernel(
    const short* __restrict__ Qg, const short* __restrict__ Kg,
    const short* __restrict__ Vt, float* __restrict__ out,
    char* __restrict__ part, int* __restrict__ cnt, int split) {
  __shared__ __align__(16) short Ks[4][64 * 64];
  __shared__ __align__(16) short Vs[4][64 * 64];
  __shared__ int lastFlag;
  const int tid = threadIdx.x;
  const int lane = tid & 63;
  const int w = tid >> 6;                        // 0..7
  const int c = lane & 15;
  const int sl = lane >> 4;

  // ---- unit decode: F(g) = ceil((g+1)/2)*ceil((g+2)/2), nch = g/2+1 ----
  int g, ch, b, uu = 0;
  if (split) {
    const int lin = (blockIdx.x & 7) * 136 + (blockIdx.x >> 3);  // XCD affinity
    b = lin / 272;
    uu = lin - b * 272;
    g = (int)(2.0f * sqrtf((float)uu));
    while (((g + 2) >> 1) * ((g + 3) >> 1) <= uu) ++g;
    while (((g + 1) >> 1) * ((g + 2) >> 1) > uu) --g;
    ch = uu - ((g + 1) >> 1) * ((g + 2) >> 1);
  } else { g = blockIdx.x; b = blockIdx.y; ch = 0; }
  const int T = 2 * (g + 1);
  const int c0 = ch * 4;
  const int c1 = (!split || c0 + 4 > T) ? T : c0 + 4;
  const int nch = split ? ((g >> 1) + 1) : 1;
  const int nt_loc = c1 - c0;                    // 1..4 tiles this block
  const int qw = g * 128 + w * 16;               // wave's 16 q-rows

  const short* Kb = Kg + (size_t)b * 4096 * 64;
  const short* Vb = Vt + (size_t)b * 64 * 4096;

  // Q frag (MFMA B-operand): lane holds Q[q=qw+c][h=sl*8+:8]
  short8 aq0, aq1;
  {
    const short* qp = Qg + (size_t)(b * 4096 + qw + c) * 64 + sl * 8;
    aq0 = *(const short8*)(qp);
    aq1 = *(const short8*)(qp + 32);
  }

  float4v o[4];
#pragma unroll
  for (int ht = 0; ht < 4; ++ht) o[ht] = (float4v){0.f, 0.f, 0.f, 0.f};
  float4v osum = {0.f, 0.f, 0.f, 0.f};           // row-sums via P x ones

  union { uint32_t u[2]; short4v s4; } one_init;
  one_init.u[0] = 0x3F803F80u;                   // bf16 1.0 x2
  one_init.u[1] = 0x3F803F80u;
  const short4v vones = one_init.s4;

  // ---- stage ALL tiles of this chunk, then ONE barrier ----
  {
    const int rw = tid >> 3;
    const int scol = ((tid & 7) ^ (rw & 7)) * 8;
#pragma unroll
    for (int tt = 0; tt < 4; ++tt) {
      if (tt < nt_loc) {
        const int kv0s = (c0 + tt) * 64;
        gld_lds16(Ks[tt] + tid * 8, Kb + (size_t)(kv0s + rw) * 64 + scol);
        gld_lds16(Vs[tt] + tid * 8, Vb + (size_t)rw * 4096 + kv0s + scol);
      }
    }
  }
  __syncthreads();                               // single drain; LDS now RO

  for (int tt = 0; tt < nt_loc; ++tt) {
    const int kv0 = (c0 + tt) * 64;
    const short* KsC = Ks[tt];
    const short* VsC = Vs[tt];

    // S^T = K Q^T: lane (c,sl) holds S[kv=kv0+16nt+4sl+i][q=qw+c]
    float4v s[4];
    __builtin_amdgcn_s_setprio(1);
#pragma unroll
    for (int nt = 0; nt < 4; ++nt) {
      const int rw = nt * 16 + c;
      short8 kb0 = *(const short8*)(KsC + rw * 64 + ((sl ^ (rw & 7)) * 8));
      short8 kb1 = *(const short8*)(KsC + rw * 64 + (((sl + 4) ^ (rw & 7)) * 8));
      float4v z = {0.f, 0.f, 0.f, 0.f};
      z = MFMA16(kb0, aq0, z);
      z = MFMA16(kb1, aq1, z);
      s[nt] = z;
    }
    __builtin_amdgcn_s_setprio(0);

    // causal mask
    if (kv0 + 63 > qw) {
      const int qg = qw + c;
#pragma unroll
      for (int nt = 0; nt < 4; ++nt)
#pragma unroll
        for (int i = 0; i < 4; ++i) {
          const int kvg = kv0 + nt * 16 + sl * 4 + i;
          s[nt][i] = (kvg <= qg) ? s[nt][i] : -1e30f;
        }
    }

    // P = exp2(s), pack pairs -> direct K=16 A-fragments
    short4v pa[4];
#pragma unroll
    for (int nt = 0; nt < 4; ++nt) {
      const float p0 = exp2f(s[nt][0]);
      const float p1 = exp2f(s[nt][1]);
      const float p2 = exp2f(s[nt][2]);
      const float p3 = exp2f(s[nt][3]);
      union { uint32_t u[2]; short4v s4; } cv;
      cv.u[0] = cvtpk(p0, p1);
      cv.u[1] = cvtpk(p2, p3);
      pa[nt] = cv.s4;
    }

    // O += P V ; osum += P x ones  (all in matrix pipe)
    __builtin_amdgcn_s_setprio(1);
#pragma unroll
    for (int ht = 0; ht < 4; ++ht) {
      const int row = ht * 16 + c;
#pragma unroll
      for (int nt = 0; nt < 4; ++nt) {
        const int slot8 = (nt * 2 + (sl >> 1)) ^ (row & 7);
        short4v vb = *(const short4v*)(VsC + row * 64 + slot8 * 8 + (sl & 1) * 4);
        o[ht] = MFMA16K16(pa[nt], vb, o[ht]);
      }
    }
#pragma unroll
    for (int nt = 0; nt < 4; ++nt)
      osum = MFMA16K16(pa[nt], vones, osum);
    __builtin_amdgcn_s_setprio(0);
  }

  if (nch == 1) {                                // single chunk: direct out
    float inv[4];
#pragma unroll
    for (int i = 0; i < 4; ++i) inv[i] = 1.0f / osum[i];
#pragma unroll
    for (int ht = 0; ht < 4; ++ht)
#pragma unroll
      for (int i = 0; i < 4; ++i) {
        const int q = qw + sl * 4 + i;
        out[(size_t)(b * 4096 + q) * 64 + ht * 16 + c] = o[ht][i] * inv[i];
      }
    return;
  }

  // partial write (bf16 o + f32 l)
  short* sp = (short*)(part + (size_t)(b * 272 + uu) * SLOT_BYTES);
  float* lp = (float*)(sp + 8192);
#pragma unroll
  for (int ht = 0; ht < 4; ++ht)
#pragma unroll
    for (int i = 0; i < 4; ++i) {
      const int row = w * 16 + sl * 4 + i;
      sp[row * 64 + ht * 16 + c] = bf16r(o[ht][i]);
    }
  if (c == 0) {
#pragma unroll
    for (int i = 0; i < 4; ++i)
      lp[w * 16 + sl * 4 + i] = osum[i];
  }

  // ---- last chunk of (b,g) combines (fixed order => deterministic) ----
  __syncthreads();
  if (tid == 0) {
    __builtin_amdgcn_fence(__ATOMIC_RELEASE, "agent");
    int old = __hip_atomic_fetch_add(&cnt[b * 32 + g], 1,
                                     __ATOMIC_RELAXED, __HIP_MEMORY_SCOPE_AGENT);
    lastFlag = (old == nch - 1);
  }
  __syncthreads();
  if (!lastFlag) return;
  __builtin_amdgcn_fence(__ATOMIC_ACQUIRE, "agent");

  const int F = ((g + 1) >> 1) * ((g + 2) >> 1);
  const char* base = part + (size_t)(b * 272 + F) * SLOT_BYTES;
  const int r = tid >> 2;                        // row 0..127
  const int cb = (tid & 3) * 16;                 // col block (16 f32)

  float L = 0.f;
  float acc[16];
#pragma unroll
  for (int k = 0; k < 16; ++k) acc[k] = 0.f;
  for (int i = 0; i < nch; ++i) {
    const short* spp = (const short*)(base + (size_t)i * SLOT_BYTES);
    L += ((const float*)(spp + 8192))[r];
    const short* sr = spp + r * 64 + cb;
    short8 v0 = *(const short8*)(sr);
    short8 v1 = *(const short8*)(sr + 8);
#pragma unroll
    for (int j = 0; j < 8; ++j) {
      acc[j] += bf2f(v0[j]);
      acc[8 + j] += bf2f(v1[j]);
    }
  }
  const float inv = 1.0f / L;
  float* op = out + (size_t)(b * 4096 + g * 128 + r) * 64 + cb;
#pragma unroll
  for (int k = 0; k < 4; ++k) {
    float4v res = {acc[k * 4] * inv, acc[k * 4 + 1] * inv,
                   acc[k * 4 + 2] * inv, acc[k * 4 + 3] * inv};
    *(float4v*)(op + k * 4) = res;
  }
}

extern "C" void kernel_launch(void* const* d_in, const int* in_sizes, int n_in,
                              void* d_out, int out_size, void* d_ws, size_t ws_size,
                              hipStream_t stream) {
  const float* x  = (const float*)d_in[0];
  const float* Wk = (const float*)d_in[1];
  const float* Wq = (const float*)d_in[2];
  const float* Wv = (const float*)d_in[3];

  char* ws = (char*)d_ws;
  short* WT = (short*)ws;                                  // 393216 B
  short* Kg = (short*)(ws + 393216);                       // 2 MB
  short* Qg = (short*)(ws + 393216 + 2097152);             // 2 MB
  short* Vt = (short*)(ws + 393216 + 2 * 2097152);         // 2 MB
  const size_t part_off = 393216 + 3 * 2097152;            // 6684672
  char* part = ws + part_off;
  const size_t cnt_off = part_off + (size_t)1088 * SLOT_BYTES;
  int* cnt = (int*)(ws + cnt_off);                         // 128 ints

  const int split = (ws_size >= cnt_off + 512) ? 1 : 0;

  prep_wt<<<dim3(16, 3), dim3(256), 0, stream>>>(Wk, Wq, Wv, WT);
  if (split) hipMemsetAsync(cnt, 0, 512, stream);
  proj_kernel<<<dim3(512), dim3(512), 0, stream>>>(x, WT, Kg, Qg, Vt);
  attn_kernel<<<split ? dim3(1088) : dim3(32, 4), dim3(512), 0, stream>>>(
      Qg, Kg, Vt, (float*)d_out, part, cnt, split);
}

// Round 22
// 56.574 us; speedup vs baseline: 1.6890x; 1.6890x over previous
//
#include <hip/hip_runtime.h>
#include <hip/hip_bf16.h>
#include <stdint.h>
#include <math.h>

typedef __attribute__((ext_vector_type(8))) short short8;
typedef __attribute__((ext_vector_type(4))) short short4v;
typedef __attribute__((ext_vector_type(4))) float float4v;

#define MFMA16(a,b,c) __builtin_amdgcn_mfma_f32_16x16x32_bf16((a),(b),(c),0,0,0)
#define MFMA16K16(a,b,c) __builtin_amdgcn_mfma_f32_16x16x16bf16_1k((a),(b),(c),0,0,0)

__device__ __forceinline__ short bf16r(float f) {
  union { float f; uint32_t u; } v; v.f = f;
  uint32_t r = v.u + 0x7fffu + ((v.u >> 16) & 1u);
  return (short)(r >> 16);
}
__device__ __forceinline__ float bf2f(short s) {
  union { float f; uint32_t u; } v; v.u = ((uint32_t)(uint16_t)s) << 16;
  return v.f;
}
// packed f32x2 -> bf16x2 (lo = a, hi = b)
__device__ __forceinline__ uint32_t cvtpk(float a, float b) {
  uint32_t r;
  asm("v_cvt_pk_bf16_f32 %0, %1, %2" : "=v"(r) : "v"(a), "v"(b));
  return r;
}

__device__ __forceinline__ void gld_lds16(void* lds, const void* g) {
  __builtin_amdgcn_global_load_lds(
      (const __attribute__((address_space(1))) uint32_t*)g,
      (__attribute__((address_space(3))) uint32_t*)lds, 16, 0, 0);
}

// ---------------- Kernel 1: W transpose+convert (LDS transpose) -------------
__global__ __launch_bounds__(256) void prep_wt(
    const float* __restrict__ Wk, const float* __restrict__ Wq,
    const float* __restrict__ Wv, short* __restrict__ WT) {
  __shared__ float tile[64][65];
  const int w = blockIdx.y;
  const int k0 = blockIdx.x * 64;
  const float* W = (w == 0) ? Wk : (w == 1) ? Wq : Wv;
  const int tid = threadIdx.x;
#pragma unroll
  for (int i = 0; i < 16; ++i) {
    int e = i * 256 + tid;
    int kk = e >> 6, hh = e & 63;
    tile[kk][hh] = W[(size_t)(k0 + kk) * 64 + hh];
  }
  __syncthreads();
#pragma unroll
  for (int i = 0; i < 16; ++i) {
    int e = i * 256 + tid;
    int hh = e >> 6, kk = e & 63;
    WT[(size_t)w * 65536 + hh * 1024 + k0 + kk] = bf16r(tile[kk][hh]);
  }
}

// ---------------- Kernel 2: projection GEMM, BM=32, 2 blocks/CU -------------
// (validated R12) 512 blocks x 512 thr; wave w: m-tile w&1, n-triple w>>1.
// Qg pre-scaled by 0.125*log2(e) so attn uses native exp2.
__global__ __launch_bounds__(512, 4) void proj_kernel(
    const float* __restrict__ x, const short* __restrict__ WT,
    short* __restrict__ Kg, short* __restrict__ Qg, short* __restrict__ Vt) {
  __shared__ __align__(16) short xs[2][32][72];
  __shared__ __align__(16) short wts[2][192 * 64];
  const int tid = threadIdx.x;
  const int lane = tid & 63;
  const int w = tid >> 6;
  const int c = lane & 15;
  const int sl = lane >> 4;
  const int mh = w & 1;
  const int nh = w >> 1;
  const int m0 = blockIdx.x * 32;

  float4v acc[3];
#pragma unroll
  for (int ni = 0; ni < 3; ++ni) acc[ni] = (float4v){0.f, 0.f, 0.f, 0.f};

  const int srow = tid >> 4;
  const int scol = (tid & 15) * 4;
  const float* xrow = x + (size_t)(m0 + srow) * 1024 + scol;

#define PSTAGE_WT(buf, kk)                                                    \
  _Pragma("unroll") for (int rr = 0; rr < 3; ++rr) {                          \
    const int chunk = rr * 512 + tid;                                         \
    const int n = chunk >> 3;                                                 \
    const int cc = chunk & 7;                                                 \
    gld_lds16(wts[buf] + chunk * 8,                                           \
              WT + (size_t)n * 1024 + (kk) + ((cc ^ (n & 7)) * 8));           \
  }
#define PWRITE_X(buf)                                                         \
  {                                                                           \
    short4v hx;                                                               \
    hx.x = bf16r(xr.x); hx.y = bf16r(xr.y);                                   \
    hx.z = bf16r(xr.z); hx.w = bf16r(xr.w);                                   \
    *(short4v*)(&xs[buf][srow][scol]) = hx;                                   \
  }

  float4v xr = *(const float4v*)(xrow);
  float4v xn = *(const float4v*)(xrow + 64);

  PSTAGE_WT(0, 0)
  PWRITE_X(0)
  __syncthreads();

  int cur = 0;
  for (int it = 0; it < 16; ++it) {
    const int k0 = it * 64;
    if (it + 1 < 16) {
      PSTAGE_WT(cur ^ 1, k0 + 64)
      xr = xn;
      PWRITE_X(cur ^ 1)
      if (it + 2 < 16) xn = *(const float4v*)(xrow + k0 + 128);
    }
    short8 a0 = *(const short8*)(&xs[cur][mh * 16 + c][sl * 8]);
    short8 a1 = *(const short8*)(&xs[cur][mh * 16 + c][32 + sl * 8]);
#pragma unroll
    for (int ni = 0; ni < 3; ++ni) {
      const int rw = (nh * 3 + ni) * 16 + c;
      short8 b0 = *(const short8*)(wts[cur] + rw * 64 + ((sl ^ (rw & 7)) * 8));
      short8 b1 = *(const short8*)(wts[cur] + rw * 64 + (((sl + 4) ^ (rw & 7)) * 8));
      acc[ni] = MFMA16(a0, b0, acc[ni]);
      acc[ni] = MFMA16(a1, b1, acc[ni]);
    }
    __syncthreads();
    cur ^= 1;
  }
#undef PSTAGE_WT
#undef PWRITE_X

  const int b = m0 >> 12;
  const int s_base = m0 & 4095;
  const float QSCALE = 0.18033688011112042f;     // 0.125 * log2(e)
#pragma unroll
  for (int ni = 0; ni < 3; ++ni) {
    const int nt = nh * 3 + ni;
    const int wsel = nt >> 2;                    // 0:K 1:Q 2:V
    const int h = (nt & 3) * 16 + c;
    const int q_local = mh * 16 + sl * 4;
    if (wsel == 2) {
      short4v pv;
      pv.x = bf16r(acc[ni].x); pv.y = bf16r(acc[ni].y);
      pv.z = bf16r(acc[ni].z); pv.w = bf16r(acc[ni].w);
      *(short4v*)(Vt + (size_t)(b * 64 + h) * 4096 + s_base + q_local) = pv;
    } else if (wsel == 1) {
#pragma unroll
      for (int i = 0; i < 4; ++i)
        Qg[(size_t)(m0 + q_local + i) * 64 + h] = bf16r(acc[ni][i] * QSCALE);
    } else {
#pragma unroll
      for (int i = 0; i < 4; ++i)
        Kg[(size_t)(m0 + q_local + i) * 64 + h] = bf16r(acc[ni][i]);
    }
  }
}

// ---------------- Kernel 3: flash attention (R20 exact — session best) ------
// 8 waves x 16 q-rows, all tiles staged up front, ONE barrier, shuffle-free
// K=16 PV, matrix-pipe lsum (P x ones). Combine stays a SEPARATE kernel:
// fusing the epilogue loop collapses the allocator to 52-64 VGPRs and
// spills the hot loop (measured R10: 64 regs/86us; R21: 52 regs/80us).
#define SLOT_BYTES 16896   // 128*64 bf16 o (16384) + 128 f32 l (512)
__global__ __launch_bounds__(512, 4) void attn_kernel(
    const short* __restrict__ Qg, const short* __restrict__ Kg,
    const short* __restrict__ Vt, float* __restrict__ out,
    char* __restrict__ part, int split) {
  __shared__ __align__(16) short Ks[4][64 * 64];
  __shared__ __align__(16) short Vs[4][64 * 64];
  const int tid = threadIdx.x;
  const int lane = tid & 63;
  const int w = tid >> 6;                        // 0..7
  const int c = lane & 15;
  const int sl = lane >> 4;

  // ---- unit decode: F(g) = ceil((g+1)/2)*ceil((g+2)/2), nch = g/2+1 ----
  int g, ch, b, uu = 0;
  if (split) {
    const int lin = (blockIdx.x & 7) * 136 + (blockIdx.x >> 3);  // XCD affinity
    b = lin / 272;
    uu = lin - b * 272;
    g = (int)(2.0f * sqrtf((float)uu));
    while (((g + 2) >> 1) * ((g + 3) >> 1) <= uu) ++g;
    while (((g + 1) >> 1) * ((g + 2) >> 1) > uu) --g;
    ch = uu - ((g + 1) >> 1) * ((g + 2) >> 1);
  } else { g = blockIdx.x; b = blockIdx.y; ch = 0; }
  const int T = 2 * (g + 1);
  const int c0 = ch * 4;
  const int c1 = (!split || c0 + 4 > T) ? T : c0 + 4;
  const int nch = split ? ((g >> 1) + 1) : 1;
  const int nt_loc = c1 - c0;                    // 1..4 tiles this block
  const int qw = g * 128 + w * 16;               // wave's 16 q-rows

  const short* Kb = Kg + (size_t)b * 4096 * 64;
  const short* Vb = Vt + (size_t)b * 64 * 4096;

  // Q frag (MFMA B-operand): lane holds Q[q=qw+c][h=sl*8+:8]
  short8 aq0, aq1;
  {
    const short* qp = Qg + (size_t)(b * 4096 + qw + c) * 64 + sl * 8;
    aq0 = *(const short8*)(qp);
    aq1 = *(const short8*)(qp + 32);
  }

  float4v o[4];
#pragma unroll
  for (int ht = 0; ht < 4; ++ht) o[ht] = (float4v){0.f, 0.f, 0.f, 0.f};
  float4v osum = {0.f, 0.f, 0.f, 0.f};           // row-sums via P x ones

  union { uint32_t u[2]; short4v s4; } one_init;
  one_init.u[0] = 0x3F803F80u;                   // bf16 1.0 x2
  one_init.u[1] = 0x3F803F80u;
  const short4v vones = one_init.s4;

  // ---- stage ALL tiles of this chunk, then ONE barrier ----
  {
    const int rw = tid >> 3;
    const int scol = ((tid & 7) ^ (rw & 7)) * 8;
#pragma unroll
    for (int tt = 0; tt < 4; ++tt) {
      if (tt < nt_loc) {
        const int kv0s = (c0 + tt) * 64;
        gld_lds16(Ks[tt] + tid * 8, Kb + (size_t)(kv0s + rw) * 64 + scol);
        gld_lds16(Vs[tt] + tid * 8, Vb + (size_t)rw * 4096 + kv0s + scol);
      }
    }
  }
  __syncthreads();                               // single drain; LDS now RO

  for (int tt = 0; tt < nt_loc; ++tt) {
    const int kv0 = (c0 + tt) * 64;
    const short* KsC = Ks[tt];
    const short* VsC = Vs[tt];

    // S^T = K Q^T: lane (c,sl) holds S[kv=kv0+16nt+4sl+i][q=qw+c]
    float4v s[4];
    __builtin_amdgcn_s_setprio(1);
#pragma unroll
    for (int nt = 0; nt < 4; ++nt) {
      const int rw = nt * 16 + c;
      short8 kb0 = *(const short8*)(KsC + rw * 64 + ((sl ^ (rw & 7)) * 8));
      short8 kb1 = *(const short8*)(KsC + rw * 64 + (((sl + 4) ^ (rw & 7)) * 8));
      float4v z = {0.f, 0.f, 0.f, 0.f};
      z = MFMA16(kb0, aq0, z);
      z = MFMA16(kb1, aq1, z);
      s[nt] = z;
    }
    __builtin_amdgcn_s_setprio(0);

    // causal mask
    if (kv0 + 63 > qw) {
      const int qg = qw + c;
#pragma unroll
      for (int nt = 0; nt < 4; ++nt)
#pragma unroll
        for (int i = 0; i < 4; ++i) {
          const int kvg = kv0 + nt * 16 + sl * 4 + i;
          s[nt][i] = (kvg <= qg) ? s[nt][i] : -1e30f;
        }
    }

    // P = exp2(s), pack pairs -> direct K=16 A-fragments (no scalar lsum)
    short4v pa[4];
#pragma unroll
    for (int nt = 0; nt < 4; ++nt) {
      const float p0 = exp2f(s[nt][0]);
      const float p1 = exp2f(s[nt][1]);
      const float p2 = exp2f(s[nt][2]);
      const float p3 = exp2f(s[nt][3]);
      union { uint32_t u[2]; short4v s4; } cv;
      cv.u[0] = cvtpk(p0, p1);
      cv.u[1] = cvtpk(p2, p3);
      pa[nt] = cv.s4;
    }

    // O += P V ; osum += P x ones  (all in matrix pipe)
    __builtin_amdgcn_s_setprio(1);
#pragma unroll
    for (int ht = 0; ht < 4; ++ht) {
      const int row = ht * 16 + c;
#pragma unroll
      for (int nt = 0; nt < 4; ++nt) {
        const int slot8 = (nt * 2 + (sl >> 1)) ^ (row & 7);
        short4v vb = *(const short4v*)(VsC + row * 64 + slot8 * 8 + (sl & 1) * 4);
        o[ht] = MFMA16K16(pa[nt], vb, o[ht]);
      }
    }
#pragma unroll
    for (int nt = 0; nt < 4; ++nt)
      osum = MFMA16K16(pa[nt], vones, osum);
    __builtin_amdgcn_s_setprio(0);
  }

  if (nch == 1) {                                // single chunk: direct out
    float inv[4];
#pragma unroll
    for (int i = 0; i < 4; ++i) inv[i] = 1.0f / osum[i];
#pragma unroll
    for (int ht = 0; ht < 4; ++ht)
#pragma unroll
      for (int i = 0; i < 4; ++i) {
        const int q = qw + sl * 4 + i;
        out[(size_t)(b * 4096 + q) * 64 + ht * 16 + c] = o[ht][i] * inv[i];
      }
  } else {
    short* sp = (short*)(part + (size_t)(b * 272 + uu) * SLOT_BYTES);
    float* lp = (float*)(sp + 8192);
#pragma unroll
    for (int ht = 0; ht < 4; ++ht)
#pragma unroll
      for (int i = 0; i < 4; ++i) {
        const int row = w * 16 + sl * 4 + i;
        sp[row * 64 + ht * 16 + c] = bf16r(o[ht][i]);
      }
    if (c == 0) {
#pragma unroll
      for (int i = 0; i < 4; ++i)
        lp[w * 16 + sl * 4 + i] = osum[i];
    }
  }
}

// ---------------- Kernel 4: split-KV combine, row-split 4x ------------------
__global__ __launch_bounds__(256) void combine_kernel(
    const char* __restrict__ part, float* __restrict__ out) {
  const int g = blockIdx.x;                      // 0..31
  const int b = blockIdx.y;
  const int N = (g >> 1) + 1;
  if (N == 1) return;                            // attn wrote direct
  const int F = ((g + 1) >> 1) * ((g + 2) >> 1);
  const char* base = part + (size_t)(b * 272 + F) * SLOT_BYTES;
  const int r = blockIdx.z * 32 + (threadIdx.x >> 3);   // row 0..127
  const int cb = (threadIdx.x & 7) * 8;                 // col block (8 f32)

  float L = 0.f;
  float acc[8];
#pragma unroll
  for (int k = 0; k < 8; ++k) acc[k] = 0.f;
  for (int i = 0; i < N; ++i) {
    const short* sp = (const short*)(base + (size_t)i * SLOT_BYTES);
    L += ((const float*)(sp + 8192))[r];
    short8 v = *(const short8*)(sp + r * 64 + cb);
#pragma unroll
    for (int j = 0; j < 8; ++j) acc[j] += bf2f(v[j]);
  }
  const float inv = 1.0f / L;
  float* op = out + (size_t)(b * 4096 + g * 128 + r) * 64 + cb;
  float4v r0 = {acc[0] * inv, acc[1] * inv, acc[2] * inv, acc[3] * inv};
  float4v r1 = {acc[4] * inv, acc[5] * inv, acc[6] * inv, acc[7] * inv};
  *(float4v*)(op) = r0;
  *(float4v*)(op + 4) = r1;
}

extern "C" void kernel_launch(void* const* d_in, const int* in_sizes, int n_in,
                              void* d_out, int out_size, void* d_ws, size_t ws_size,
                              hipStream_t stream) {
  const float* x  = (const float*)d_in[0];
  const float* Wk = (const float*)d_in[1];
  const float* Wq = (const float*)d_in[2];
  const float* Wv = (const float*)d_in[3];

  char* ws = (char*)d_ws;
  short* WT = (short*)ws;                                  // 393216 B
  short* Kg = (short*)(ws + 393216);                       // 2 MB
  short* Qg = (short*)(ws + 393216 + 2097152);             // 2 MB
  short* Vt = (short*)(ws + 393216 + 2 * 2097152);         // 2 MB
  const size_t part_off = 393216 + 3 * 2097152;            // 6684672
  char* part = ws + part_off;

  const int split = (ws_size >= part_off + (size_t)1088 * SLOT_BYTES) ? 1 : 0;

  prep_wt<<<dim3(16, 3), dim3(256), 0, stream>>>(Wk, Wq, Wv, WT);
  proj_kernel<<<dim3(512), dim3(512), 0, stream>>>(x, WT, Kg, Qg, Vt);
  attn_kernel<<<split ? dim3(1088) : dim3(32, 4), dim3(512), 0, stream>>>(
      Qg, Kg, Vt, (float*)d_out, part, split);
  if (split)
    combine_kernel<<<dim3(32, 4, 4), dim3(256), 0, stream>>>(part, (float*)d_out);
}